// Round 6
// baseline (410.515 us; speedup 1.0000x reference)
//
#include <hip/hip_runtime.h>
#include <cstdint>
#include <cstddef>

#define BATCH  4
#define RUNITS 128
#define CC     129            // 1 + RUNITS
#define MM     5
#define SEG    136            // ushorts per b-segment (c 0..128 real, 129..135 zero)
#define US     544            // ushorts per node row = 4*SEG (1088B)
#define KB     672            // GEMM K: 20 steps of 32 (c<128) + 1 step (c==128 x 5m)

typedef unsigned int  uint32;
typedef unsigned short ushort16;
typedef __attribute__((ext_vector_type(8))) short short8;
typedef __attribute__((ext_vector_type(4))) float f32x4;

__device__ inline float bflo(uint32 u){ return __uint_as_float(u << 16); }
__device__ inline float bfhi(uint32 u){ return __uint_as_float(u & 0xFFFF0000u); }
__device__ inline ushort16 f2bf(float f){
  uint32 u = __float_as_uint(f);
  return (ushort16)((u + 0x7FFFu + ((u >> 16) & 1u)) >> 16);
}
__device__ inline float bf2f(ushort16 v){ return __uint_as_float(((uint32)v) << 16); }
__device__ inline int sw4(int r){ return (r ^ (r >> 2)) & 3; }

// ---------------- graph prep ----------------

__global__ void k_zero_i(int* p, int n) {
  int i = blockIdx.x*blockDim.x + threadIdx.x;
  if (i < n) p[i] = 0;
}

__global__ void k_deg_cnt(const int* __restrict__ src, const int* __restrict__ dst,
                          const float* __restrict__ w, int E,
                          float* deg_out, float* deg_in, int* cnt_f, int* cnt_b) {
  int e = blockIdx.x*blockDim.x + threadIdx.x;
  if (e >= E) return;
  int s = src[e], d = dst[e]; float we = w[e];
  atomicAdd(&deg_out[s], we);
  atomicAdd(&deg_in[d], we);
  atomicAdd(&cnt_f[s], 1);
  atomicAdd(&cnt_b[d], 1);
}

// 3-phase scan
__global__ __launch_bounds__(256) void k_scansum(
    const int* __restrict__ cnt_f, const int* __restrict__ cnt_b, int* bsum, int n) {
  const int* cnt = blockIdx.y ? cnt_b : cnt_f;
  int tid = threadIdx.x, lane = tid & 63, wv = tid >> 6;
  int i = blockIdx.x*256 + tid;
  int v = (i < n) ? cnt[i] : 0;
  #pragma unroll
  for (int d = 32; d > 0; d >>= 1) v += __shfl_down(v, d);
  __shared__ int sm[4];
  if (lane == 0) sm[wv] = v;
  __syncthreads();
  if (tid == 0) bsum[blockIdx.y*40 + blockIdx.x] = sm[0]+sm[1]+sm[2]+sm[3];
}

__global__ __launch_bounds__(64) void k_scanmid(
    const int* bsum, int* bofs, int* ptrF, int* ptrB, int n, int nb) {
  int lane = threadIdx.x;
  for (int a = 0; a < 2; ++a) {
    int v = (lane < nb) ? bsum[a*nb + lane] : 0;
    int x = v;
    #pragma unroll
    for (int d = 1; d < 64; d <<= 1) { int t = __shfl_up(x, d); if (lane >= d) x += t; }
    if (lane < nb) bofs[a*nb + lane] = x - v;
    if (lane == nb - 1) { if (a) ptrB[n] = x; else ptrF[n] = x; }
  }
}

__global__ __launch_bounds__(256) void k_scanapply(
    const int* __restrict__ cnt_f, const int* __restrict__ cnt_b, const int* __restrict__ bofs,
    int* ptrF, int* curF, int* ptrB, int* curB, int n) {
  int a = blockIdx.y;
  const int* cnt = a ? cnt_b : cnt_f;
  int* ptr = a ? ptrB : ptrF;
  int* cur = a ? curB : curF;
  int tid = threadIdx.x, lane = tid & 63, wv = tid >> 6;
  int i = blockIdx.x*256 + tid;
  int v = (i < n) ? cnt[i] : 0;
  int x = v;
  #pragma unroll
  for (int d = 1; d < 64; d <<= 1) { int t = __shfl_up(x, d); if (lane >= d) x += t; }
  __shared__ int ws[4];
  __shared__ int wo[4];
  if (lane == 63) ws[wv] = x;
  __syncthreads();
  if (tid == 0) { int s = 0; for (int k = 0; k < 4; ++k) { wo[k] = s; s += ws[k]; } }
  __syncthreads();
  int excl = x - v + wo[wv] + bofs[a*40 + blockIdx.x];
  if (i < n) { ptr[i] = excl; cur[i] = excl; }
}

__global__ void k_fill(const int* __restrict__ src, const int* __restrict__ dst,
                       const float* __restrict__ w, int E,
                       const float* __restrict__ deg_out, const float* __restrict__ deg_in,
                       int* cur_f, int* cur_b,
                       int* col_f, float* val_f, int* col_b, float* val_b) {
  int e = blockIdx.x*blockDim.x + threadIdx.x;
  if (e >= E) return;
  int s = src[e], d = dst[e]; float we = w[e];
  int pf = atomicAdd(&cur_f[s], 1);
  col_f[pf] = d; val_f[pf] = we / deg_out[s];
  int pb = atomicAdd(&cur_b[d], 1);
  col_b[pb] = s; val_b[pb] = we / deg_in[d];
}

// ---------------- weight pack: Bt[o][k], K=672 layout ----------------

__global__ void k_packw(const float* __restrict__ W, ushort16* __restrict__ Bt, int ncol) {
  int idx = blockIdx.x*blockDim.x + threadIdx.x;
  int total = ncol * KB;
  if (idx >= total) return;
  int o = idx / KB, k = idx - o*KB;
  int s = k >> 5, j = k & 31;
  float v = 0.f;
  if (s < 20) {
    int m = s >> 2, c = (s & 3)*32 + j;
    v = W[(size_t)(c*MM + m)*ncol + o];
  } else if (j < MM) {
    v = W[(size_t)(RUNITS*MM + j)*ncol + o];
  }
  Bt[idx] = f2bf(v);
}

// ---------------- build x0 ----------------

template<bool HBF>
__global__ __launch_bounds__(256) void k_build_x0(
    const float* __restrict__ inp, const void* __restrict__ hsrc,
    ushort16* __restrict__ x0, int N) {
  int wv = threadIdx.x >> 6, lane = threadIdx.x & 63;
  int n = blockIdx.x*4 + wv;
  if (n >= N) return;
  const float* hf = (const float*)hsrc;
  const ushort16* hb = (const ushort16*)hsrc;
  size_t ob = (size_t)n*US;
  for (int ch = lane; ch < 68; ch += 64) {
    int b = ch / 17, l = ch - b*17;
    size_t r = (size_t)b*N + n;
    short8 pk;
    #pragma unroll
    for (int s = 0; s < 8; ++s) {
      int c = l*8 + s;
      float x = 0.f;
      if (c == 0) x = inp[r];
      else if (c <= RUNITS) x = HBF ? bf2f(hb[r*RUNITS + (c-1)]) : hf[r*RUNITS + (c-1)];
      pk[s] = (short)f2bf(x);
    }
    *(short8*)&x0[ob + ch*8] = pk;
  }
}

// ---------------- fused dual SPMM ----------------

template<bool HY>
__global__ __launch_bounds__(256) void k_spmm2(
    const int* __restrict__ ptrF, const int* __restrict__ colF, const float* __restrict__ valF,
    const ushort16* __restrict__ XF, ushort16* __restrict__ outF,
    const int* __restrict__ ptrB, const int* __restrict__ colB, const float* __restrict__ valB,
    const ushort16* __restrict__ XB, ushort16* __restrict__ outB,
    const ushort16* __restrict__ Y0, int N, int sgrid, float alpha, float beta) {
  int bid = blockIdx.x;
  bool jb = bid >= sgrid;
  const int* ptr = jb ? ptrB : ptrF;
  const int* col = jb ? colB : colF;
  const float* val = jb ? valB : valF;
  const ushort16* X = jb ? XB : XF;
  ushort16* out = jb ? outB : outF;
  int wv = threadIdx.x >> 6, lane = threadIdx.x & 63;
  int n = (bid - (jb ? sgrid : 0))*4 + wv;
  if (n >= N) return;
  int s = ptr[n], e = ptr[n+1];
  int ch0 = lane*8, ch1 = (64+lane)*8;
  bool t4 = lane < 4;
  float a0[8] = {0,0,0,0,0,0,0,0};
  float a1[8] = {0,0,0,0,0,0,0,0};
  #pragma unroll 4
  for (int i = s; i < e; ++i) {
    int c = col[i]; float v = val[i];
    const ushort16* Xr = X + (size_t)c*US;
    uint4 u = *(const uint4*)(Xr + ch0);
    a0[0] += v*bflo(u.x); a0[1] += v*bfhi(u.x);
    a0[2] += v*bflo(u.y); a0[3] += v*bfhi(u.y);
    a0[4] += v*bflo(u.z); a0[5] += v*bfhi(u.z);
    a0[6] += v*bflo(u.w); a0[7] += v*bfhi(u.w);
    if (t4) {
      uint4 u2 = *(const uint4*)(Xr + ch1);
      a1[0] += v*bflo(u2.x); a1[1] += v*bfhi(u2.x);
      a1[2] += v*bflo(u2.y); a1[3] += v*bfhi(u2.y);
      a1[4] += v*bflo(u2.z); a1[5] += v*bfhi(u2.z);
      a1[6] += v*bflo(u2.w); a1[7] += v*bfhi(u2.w);
    }
  }
  size_t ob = (size_t)n*US;
  {
    float r[8];
    if (HY) {
      uint4 y = *(const uint4*)(Y0 + ob + ch0);
      r[0] = alpha*a0[0] + beta*bflo(y.x); r[1] = alpha*a0[1] + beta*bfhi(y.x);
      r[2] = alpha*a0[2] + beta*bflo(y.y); r[3] = alpha*a0[3] + beta*bfhi(y.y);
      r[4] = alpha*a0[4] + beta*bflo(y.z); r[5] = alpha*a0[5] + beta*bfhi(y.z);
      r[6] = alpha*a0[6] + beta*bflo(y.w); r[7] = alpha*a0[7] + beta*bfhi(y.w);
    } else {
      #pragma unroll
      for (int q = 0; q < 8; ++q) r[q] = alpha*a0[q];
    }
    short8 pk;
    #pragma unroll
    for (int q = 0; q < 8; ++q) pk[q] = (short)f2bf(r[q]);
    *(short8*)&out[ob + ch0] = pk;
  }
  if (t4) {
    float r[8];
    if (HY) {
      uint4 y = *(const uint4*)(Y0 + ob + ch1);
      r[0] = alpha*a1[0] + beta*bflo(y.x); r[1] = alpha*a1[1] + beta*bfhi(y.x);
      r[2] = alpha*a1[2] + beta*bflo(y.y); r[3] = alpha*a1[3] + beta*bfhi(y.y);
      r[4] = alpha*a1[4] + beta*bflo(y.z); r[5] = alpha*a1[5] + beta*bfhi(y.z);
      r[6] = alpha*a1[6] + beta*bflo(y.w); r[7] = alpha*a1[7] + beta*bfhi(y.w);
    } else {
      #pragma unroll
      for (int q = 0; q < 8; ++q) r[q] = alpha*a1[q];
    }
    short8 pk;
    #pragma unroll
    for (int q = 0; q < 8; ++q) pk[q] = (short)f2bf(r[q]);
    *(short8*)&out[ob + ch1] = pk;
  }
}

// ---------------- gates GEMM: tile 64x256, 512 thr, 8 waves (2x4), wave 32x64 ----------------
// LDS rows are 32 ushorts (64B) with XOR chunk swizzle -> <=2-way banks.

__global__ __launch_bounds__(512, 4) void k_gemm_g(
    const ushort16* __restrict__ xall, const ushort16* __restrict__ Bt,
    const float* __restrict__ bias, const float* __restrict__ hx,
    ushort16* __restrict__ rh, ushort16* __restrict__ ub, int N, int BN) {
  __shared__ __align__(16) ushort16 As[2][64*32];
  __shared__ __align__(16) ushort16 Bs[2][256*32];
  int tid = threadIdx.x, lane = tid & 63, wv = tid >> 6;
  int wm = wv >> 2, wn = wv & 3;
  int fr = lane & 15, g = lane >> 4;
  int R0 = blockIdx.x*64;
  const size_t mstride = (size_t)N*US;

  // A staging: tid<256, row rA, chunk qA
  int rA = tid >> 2, qA = tid & 3;
  bool aact = tid < 256;
  int gr = R0 + rA; if (gr >= BN) gr = BN - 1;
  int bA = gr / N, nA = gr - bA*N;
  const ushort16* aPt = xall + (size_t)nA*US + bA*SEG + qA*8;
  int aofs = rA*32 + ((qA ^ sw4(rA)) << 3);

  // B staging: col cB, 2 chunks {2q2, 2q2+1}
  int cB = tid >> 1, q2 = tid & 1;
  const ushort16* bPt = Bt + (size_t)cB*KB + q2*16;
  int bofs0 = cB*32 + (((2*q2)   ^ sw4(cB)) << 3);
  int bofs1 = cB*32 + (((2*q2+1) ^ sw4(cB)) << 3);

  f32x4 acc[2][4];
  #pragma unroll
  for (int i = 0; i < 2; ++i)
    #pragma unroll
    for (int j = 0; j < 4; ++j) acc[i][j] = (f32x4){0.f,0.f,0.f,0.f};

  uint4 ra, rb0, rb1;
  if (aact) ra = *(const uint4*)aPt;
  rb0 = *(const uint4*)bPt;
  rb1 = *(const uint4*)(bPt + 8);

  int buf = 0;
  for (int s = 0; s < 20; ++s) {
    if (aact) *(uint4*)&As[buf][aofs] = ra;
    *(uint4*)&Bs[buf][bofs0] = rb0;
    *(uint4*)&Bs[buf][bofs1] = rb1;
    __syncthreads();
    if (s < 19) {
      int s1 = s + 1;
      int m = s1 >> 2, cb = (s1 & 3)*32;
      if (aact) ra = *(const uint4*)(aPt + (size_t)m*mstride + cb);
      rb0 = *(const uint4*)(bPt + s1*32);
      rb1 = *(const uint4*)(bPt + s1*32 + 8);
    }
    short8 af[2], bfv[4];
    #pragma unroll
    for (int i = 0; i < 2; ++i) {
      int rr = wm*32 + i*16 + fr;
      af[i] = *(const short8*)&As[buf][rr*32 + ((g ^ sw4(rr)) << 3)];
    }
    #pragma unroll
    for (int j = 0; j < 4; ++j) {
      int cc = wn*64 + j*16 + fr;
      bfv[j] = *(const short8*)&Bs[buf][cc*32 + ((g ^ sw4(cc)) << 3)];
    }
    #pragma unroll
    for (int i = 0; i < 2; ++i)
      #pragma unroll
      for (int j = 0; j < 4; ++j)
        acc[i][j] = __builtin_amdgcn_mfma_f32_16x16x32_bf16(af[i], bfv[j], acc[i][j], 0, 0, 0);
    buf ^= 1;
  }
  // tail step s=20: c==128 channel, 5 levels in chunk 0
  {
    rb0 = *(const uint4*)(bPt + 20*32);
    rb1 = *(const uint4*)(bPt + 20*32 + 8);
    *(uint4*)&Bs[buf][bofs0] = rb0;
    *(uint4*)&Bs[buf][bofs1] = rb1;
    if (tid < 64) {
      int r = tid, gr2 = R0 + r; if (gr2 >= BN) gr2 = BN - 1;
      int b2 = gr2 / N, n2 = gr2 - b2*N;
      const ushort16* base = xall + (size_t)n2*US + b2*SEG + 128;
      short8 v = {0,0,0,0,0,0,0,0};
      #pragma unroll
      for (int m = 0; m < MM; ++m) v[m] = (short)base[(size_t)m*mstride];
      short8 z = {0,0,0,0,0,0,0,0};
      *(short8*)&As[buf][r*32 + ((0 ^ sw4(r)) << 3)] = v;
      *(short8*)&As[buf][r*32 + ((1 ^ sw4(r)) << 3)] = z;
      *(short8*)&As[buf][r*32 + ((2 ^ sw4(r)) << 3)] = z;
      *(short8*)&As[buf][r*32 + ((3 ^ sw4(r)) << 3)] = z;
    }
    __syncthreads();
    short8 af[2], bfv[4];
    #pragma unroll
    for (int i = 0; i < 2; ++i) {
      int rr = wm*32 + i*16 + fr;
      af[i] = *(const short8*)&As[buf][rr*32 + ((g ^ sw4(rr)) << 3)];
    }
    #pragma unroll
    for (int j = 0; j < 4; ++j) {
      int cc = wn*64 + j*16 + fr;
      bfv[j] = *(const short8*)&Bs[buf][cc*32 + ((g ^ sw4(cc)) << 3)];
    }
    #pragma unroll
    for (int i = 0; i < 2; ++i)
      #pragma unroll
      for (int j = 0; j < 4; ++j)
        acc[i][j] = __builtin_amdgcn_mfma_f32_16x16x32_bf16(af[i], bfv[j], acc[i][j], 0, 0, 0);
  }
  // epilogue: o<128 -> rh = sig*hx (bf16); o>=128 -> ub = sig (bf16)
  #pragma unroll
  for (int i = 0; i < 2; ++i) {
    #pragma unroll
    for (int q = 0; q < 4; ++q) {
      int row = R0 + wm*32 + i*16 + g*4 + q;
      if (row >= BN) continue;
      #pragma unroll
      for (int j = 0; j < 4; ++j) {
        int o = wn*64 + j*16 + fr;
        float gv = acc[i][j][q] + bias[o];
        float sg = 1.f/(1.f + expf(-gv));
        if (o < RUNITS)
          rh[(size_t)row*RUNITS + o] = f2bf(sg * hx[(size_t)row*RUNITS + o]);
        else
          ub[(size_t)row*RUNITS + (o - RUNITS)] = f2bf(sg);
      }
    }
  }
}

// ---------------- cand GEMM: tile 64x128, 256 thr, 4 waves (2x2), wave 32x64, fused GRU+proj ----------------

__global__ __launch_bounds__(256, 4) void k_gemm_c(
    const ushort16* __restrict__ xall, const ushort16* __restrict__ Bt,
    const float* __restrict__ bias, const float* __restrict__ hx,
    const ushort16* __restrict__ ub, float* __restrict__ outh,
    float* __restrict__ outy, const float* __restrict__ wpj, int N, int BN) {
  __shared__ __align__(16) ushort16 As[2][64*32];
  __shared__ __align__(16) ushort16 Bs[2][128*32];
  int tid = threadIdx.x, lane = tid & 63, wv = tid >> 6;
  int wm = wv >> 1, wn = wv & 1;
  int fr = lane & 15, g = lane >> 4;
  int R0 = blockIdx.x*64;
  const size_t mstride = (size_t)N*US;

  int rA = tid >> 2, qA = tid & 3;
  int gr = R0 + rA; if (gr >= BN) gr = BN - 1;
  int bA = gr / N, nA = gr - bA*N;
  const ushort16* aPt = xall + (size_t)nA*US + bA*SEG + qA*8;
  int aofs = rA*32 + ((qA ^ sw4(rA)) << 3);

  int cB = tid >> 1, q2 = tid & 1;
  const ushort16* bPt = Bt + (size_t)cB*KB + q2*16;
  int bofs0 = cB*32 + (((2*q2)   ^ sw4(cB)) << 3);
  int bofs1 = cB*32 + (((2*q2+1) ^ sw4(cB)) << 3);

  f32x4 acc[2][4];
  #pragma unroll
  for (int i = 0; i < 2; ++i)
    #pragma unroll
    for (int j = 0; j < 4; ++j) acc[i][j] = (f32x4){0.f,0.f,0.f,0.f};

  uint4 ra, rb0, rb1;
  ra  = *(const uint4*)aPt;
  rb0 = *(const uint4*)bPt;
  rb1 = *(const uint4*)(bPt + 8);

  int buf = 0;
  for (int s = 0; s < 20; ++s) {
    *(uint4*)&As[buf][aofs] = ra;
    *(uint4*)&Bs[buf][bofs0] = rb0;
    *(uint4*)&Bs[buf][bofs1] = rb1;
    __syncthreads();
    if (s < 19) {
      int s1 = s + 1;
      int m = s1 >> 2, cb = (s1 & 3)*32;
      ra  = *(const uint4*)(aPt + (size_t)m*mstride + cb);
      rb0 = *(const uint4*)(bPt + s1*32);
      rb1 = *(const uint4*)(bPt + s1*32 + 8);
    }
    short8 af[2], bfv[4];
    #pragma unroll
    for (int i = 0; i < 2; ++i) {
      int rr = wm*32 + i*16 + fr;
      af[i] = *(const short8*)&As[buf][rr*32 + ((g ^ sw4(rr)) << 3)];
    }
    #pragma unroll
    for (int j = 0; j < 4; ++j) {
      int cc = wn*64 + j*16 + fr;
      bfv[j] = *(const short8*)&Bs[buf][cc*32 + ((g ^ sw4(cc)) << 3)];
    }
    #pragma unroll
    for (int i = 0; i < 2; ++i)
      #pragma unroll
      for (int j = 0; j < 4; ++j)
        acc[i][j] = __builtin_amdgcn_mfma_f32_16x16x32_bf16(af[i], bfv[j], acc[i][j], 0, 0, 0);
    buf ^= 1;
  }
  {
    rb0 = *(const uint4*)(bPt + 20*32);
    rb1 = *(const uint4*)(bPt + 20*32 + 8);
    *(uint4*)&Bs[buf][bofs0] = rb0;
    *(uint4*)&Bs[buf][bofs1] = rb1;
    if (tid < 64) {
      int r = tid, gr2 = R0 + r; if (gr2 >= BN) gr2 = BN - 1;
      int b2 = gr2 / N, n2 = gr2 - b2*N;
      const ushort16* base = xall + (size_t)n2*US + b2*SEG + 128;
      short8 v = {0,0,0,0,0,0,0,0};
      #pragma unroll
      for (int m = 0; m < MM; ++m) v[m] = (short)base[(size_t)m*mstride];
      short8 z = {0,0,0,0,0,0,0,0};
      *(short8*)&As[buf][r*32 + ((0 ^ sw4(r)) << 3)] = v;
      *(short8*)&As[buf][r*32 + ((1 ^ sw4(r)) << 3)] = z;
      *(short8*)&As[buf][r*32 + ((2 ^ sw4(r)) << 3)] = z;
      *(short8*)&As[buf][r*32 + ((3 ^ sw4(r)) << 3)] = z;
    }
    __syncthreads();
    short8 af[2], bfv[4];
    #pragma unroll
    for (int i = 0; i < 2; ++i) {
      int rr = wm*32 + i*16 + fr;
      af[i] = *(const short8*)&As[buf][rr*32 + ((g ^ sw4(rr)) << 3)];
    }
    #pragma unroll
    for (int j = 0; j < 4; ++j) {
      int cc = wn*64 + j*16 + fr;
      bfv[j] = *(const short8*)&Bs[buf][cc*32 + ((g ^ sw4(cc)) << 3)];
    }
    #pragma unroll
    for (int i = 0; i < 2; ++i)
      #pragma unroll
      for (int j = 0; j < 4; ++j)
        acc[i][j] = __builtin_amdgcn_mfma_f32_16x16x32_bf16(af[i], bfv[j], acc[i][j], 0, 0, 0);
  }
  // epilogue: GRU combine + fused projection partial
  #pragma unroll
  for (int i = 0; i < 2; ++i) {
    #pragma unroll
    for (int q = 0; q < 4; ++q) {
      int row = R0 + wm*32 + i*16 + g*4 + q;
      bool rok = row < BN;
      float pj = 0.f;
      #pragma unroll
      for (int j = 0; j < 4; ++j) {
        int o = wn*64 + j*16 + fr;
        float gv = acc[i][j][q] + bias[o];
        float cv = tanhf(gv);
        if (rok) {
          float uu = bf2f(ub[(size_t)row*RUNITS + o]);
          float hh = hx[(size_t)row*RUNITS + o];
          float nh = uu*hh + (1.f - uu)*cv;
          outh[(size_t)row*RUNITS + o] = nh;
          pj += nh * wpj[o];
        }
      }
      #pragma unroll
      for (int d = 1; d < 16; d <<= 1) pj += __shfl_xor(pj, d);
      if (rok && fr == 0) atomicAdd(&outy[row], pj);
    }
  }
}

__global__ void k_inity(float* y, const float* bp, int n) {
  int i = blockIdx.x*blockDim.x + threadIdx.x;
  if (i < n) y[i] = bp[0];
}

// ---------------- launcher ----------------

extern "C" void kernel_launch(void* const* d_in, const int* in_sizes, int n_in,
                              void* d_out, int out_size, void* d_ws, size_t ws_size,
                              hipStream_t stream) {
  const float* inputs = (const float*)d_in[0];
  const float* hidden = (const float*)d_in[1];
  const int*   esrc   = (const int*)d_in[2];
  const int*   edst   = (const int*)d_in[3];
  const float* ew     = (const float*)d_in[4];
  const float* Wg     = (const float*)d_in[5];
  const float* bg     = (const float*)d_in[6];
  const float* Wc     = (const float*)d_in[7];
  const float* bc     = (const float*)d_in[8];
  const float* Wpj    = (const float*)d_in[9];
  const float* bpj    = (const float*)d_in[10];

  const int N  = in_sizes[0] / BATCH;
  const int E  = in_sizes[2];
  const int BN = BATCH * N;

  char* p = (char*)d_ws;
  auto alloc = [&](size_t bytes) -> void* {
    void* r = (void*)p;
    p += (bytes + 255) & ~(size_t)255;
    return r;
  };

  float* deg_out = (float*)alloc((size_t)4*N*sizeof(float));
  float* deg_in  = deg_out + N;
  int*   cnt_f   = (int*)(deg_out + 2*(size_t)N);
  int*   cnt_b   = cnt_f + N;
  int*   ptr_f   = (int*)alloc((size_t)(N+1)*sizeof(int));
  int*   ptr_b   = (int*)alloc((size_t)(N+1)*sizeof(int));
  int*   cur_f   = (int*)alloc((size_t)N*sizeof(int));
  int*   cur_b   = (int*)alloc((size_t)N*sizeof(int));
  int*   col_f   = (int*)alloc((size_t)E*sizeof(int));
  int*   col_b   = (int*)alloc((size_t)E*sizeof(int));
  float* val_f   = (float*)alloc((size_t)E*sizeof(float));
  float* val_b   = (float*)alloc((size_t)E*sizeof(float));
  int*   bsum    = (int*)alloc(80*sizeof(int));
  int*   bofs    = (int*)alloc(80*sizeof(int));
  ushort16* WtG  = (ushort16*)alloc((size_t)2*RUNITS*KB*sizeof(ushort16));
  ushort16* WtC  = (ushort16*)alloc((size_t)RUNITS*KB*sizeof(ushort16));
  ushort16* xall = (ushort16*)alloc((size_t)MM*N*US*sizeof(ushort16));
  ushort16* rh   = (ushort16*)alloc((size_t)BN*RUNITS*sizeof(ushort16));
  ushort16* ub   = (ushort16*)alloc((size_t)BN*RUNITS*sizeof(ushort16));

  float* out_y = (float*)d_out;
  float* out_h = out_y + BN;

  ushort16* x0 = xall;
  ushort16* x1 = xall + (size_t)1*N*US;
  ushort16* x2 = xall + (size_t)2*N*US;
  ushort16* x3 = xall + (size_t)3*N*US;
  ushort16* x4 = xall + (size_t)4*N*US;

  const int TB = 256;
  int nb = (N + 255)/256;
  k_zero_i<<<(4*N+TB-1)/TB, TB, 0, stream>>>((int*)deg_out, 4*N);
  k_deg_cnt<<<(E+TB-1)/TB, TB, 0, stream>>>(esrc, edst, ew, E, deg_out, deg_in, cnt_f, cnt_b);
  k_scansum<<<dim3(nb,2), TB, 0, stream>>>(cnt_f, cnt_b, bsum, N);
  k_scanmid<<<1, 64, 0, stream>>>(bsum, bofs, ptr_f, ptr_b, N, nb);
  k_scanapply<<<dim3(nb,2), TB, 0, stream>>>(cnt_f, cnt_b, bofs, ptr_f, cur_f, ptr_b, cur_b, N);
  k_fill<<<(E+TB-1)/TB, TB, 0, stream>>>(esrc, edst, ew, E, deg_out, deg_in,
                                         cur_f, cur_b, col_f, val_f, col_b, val_b);
  k_packw<<<(2*RUNITS*KB+TB-1)/TB, TB, 0, stream>>>(Wg, WtG, 2*RUNITS);
  k_packw<<<(RUNITS*KB+TB-1)/TB, TB, 0, stream>>>(Wc, WtC, RUNITS);
  k_inity<<<(BN+TB-1)/TB, TB, 0, stream>>>(out_y, bpj, BN);

  int sgrid = (N + 3) / 4;
  int gx = (BN + 63) / 64;

  // ---- gates gconv ----
  k_build_x0<false><<<sgrid, TB, 0, stream>>>(inputs, hidden, x0, N);
  k_spmm2<false><<<2*sgrid, TB, 0, stream>>>(ptr_f, col_f, val_f, x0, x1,
                                             ptr_b, col_b, val_b, x0, x3,
                                             x0, N, sgrid, 1.f, 0.f);
  k_spmm2<true ><<<2*sgrid, TB, 0, stream>>>(ptr_f, col_f, val_f, x1, x2,
                                             ptr_b, col_b, val_b, x3, x4,
                                             x0, N, sgrid, 2.f, -1.f);
  k_gemm_g<<<dim3(gx), 512, 0, stream>>>(xall, WtG, bg, hidden, rh, ub, N, BN);

  // ---- candidate gconv ----
  k_build_x0<true><<<sgrid, TB, 0, stream>>>(inputs, rh, x0, N);
  k_spmm2<false><<<2*sgrid, TB, 0, stream>>>(ptr_f, col_f, val_f, x0, x1,
                                             ptr_b, col_b, val_b, x0, x3,
                                             x0, N, sgrid, 1.f, 0.f);
  k_spmm2<true ><<<2*sgrid, TB, 0, stream>>>(ptr_f, col_f, val_f, x1, x2,
                                             ptr_b, col_b, val_b, x3, x4,
                                             x0, N, sgrid, 2.f, -1.f);
  k_gemm_c<<<dim3(gx), TB, 0, stream>>>(xall, WtC, bc, hidden, ub,
                                        out_h, out_y, Wpj, N, BN);
}